// Round 1
// baseline (90.146 us; speedup 1.0000x reference)
//
#include <hip/hip_runtime.h>

// LaneATT greedy line-NMS, lazy formulation.
// n <= 8192 proposals, 77 cols: [0:2] misc, [2] start_y, [3] start_x,
// [4] length, [5:77] xs (72 offsets). Output: 8 rows x 78 (proposal+score)
// + num_kept as float. Single block, single launch.

#define NTH     1024
#define SLOTS   8          // n <= NTH*SLOTS = 8192
#define NWAVES  (NTH / 64)
#define N_OFF   72
#define NSTRIP  71
#define PROW    77
#define MAXK    16

__global__ __launch_bounds__(NTH, 1) void lane_nms(
    const float* __restrict__ prop,
    const float* __restrict__ scores,
    const int* __restrict__ p_thres,
    const int* __restrict__ p_topk,
    float* __restrict__ out,
    int n, int out_rows)
{
    const int tid  = threadIdx.x;
    const int lane = tid & 63;
    const int wv   = tid >> 6;

    __shared__ unsigned long long s_wmax[NWAVES];
    __shared__ unsigned long long s_winner;
    __shared__ float s_cxs[N_OFF];
    __shared__ int   s_cs, s_ce, s_sup;
    __shared__ float s_kxs[MAXK][N_OFF];
    __shared__ int   s_ks[MAXK], s_ke[MAXK];

    const float thr = (float)(*p_thres);
    int topk = *p_topk;
    if (topk > out_rows) topk = out_rows;
    if (topk > MAXK)     topk = MAXK;

    // Keys: (score_bits << 32) | (0xFFFFFFFF - idx). Scores are positive
    // floats -> bit pattern is order-preserving. Tie on score -> smaller
    // index wins (matches JAX stable argsort). Removed -> key = 0.
    unsigned long long key[SLOTS];
#pragma unroll
    for (int j = 0; j < SLOTS; ++j) {
        int idx = tid + j * NTH;
        if (idx < n) {
            unsigned sb = __float_as_uint(scores[idx]);
            key[j] = ((unsigned long long)sb << 32) |
                     (unsigned long long)(0xFFFFFFFFu - (unsigned)idx);
        } else {
            key[j] = 0ULL;
        }
    }

    int kept = 0;
    for (;;) {
        // ---- block-wide argmax over alive keys ----
        unsigned long long m = 0ULL;
#pragma unroll
        for (int j = 0; j < SLOTS; ++j) m = key[j] > m ? key[j] : m;
#pragma unroll
        for (int off = 32; off > 0; off >>= 1) {
            unsigned long long o = __shfl_down(m, off);
            m = o > m ? o : m;
        }
        if (lane == 0) s_wmax[wv] = m;
        __syncthreads();
        if (wv == 0) {
            unsigned long long m2 = (lane < NWAVES) ? s_wmax[lane] : 0ULL;
#pragma unroll
            for (int off = NWAVES / 2; off > 0; off >>= 1) {
                unsigned long long o = __shfl_down(m2, off);
                m2 = o > m2 ? o : m2;
            }
            if (lane == 0) s_winner = m2;
        }
        __syncthreads();
        unsigned long long wk = s_winner;
        if (wk == 0ULL) break;                       // pool exhausted (uniform)
        int w = (int)(0xFFFFFFFFu - (unsigned)(wk & 0xFFFFFFFFu));

        // mark winner removed (register array: unrolled compare, no scratch)
        if ((w & (NTH - 1)) == tid) {
            int slot = w >> 10;
#pragma unroll
            for (int j = 0; j < SLOTS; ++j) if (j == slot) key[j] = 0ULL;
        }

        // ---- fetch candidate geometry ----
        if (tid < N_OFF) s_cxs[tid] = prop[(size_t)w * PROW + 5 + tid];
        if (tid == 0) {
            float sy = prop[(size_t)w * PROW + 2];
            float ln = prop[(size_t)w * PROW + 4];
            int s = (int)rintf(sy * (float)NSTRIP);    // round half-even == jnp.round
            int e = s + (int)rintf(ln) - 1;
            if (e > NSTRIP) e = NSTRIP;
            s_cs = s; s_ce = e;
            s_sup = 0;
        }
        __syncthreads();

        // ---- check candidate vs kept rows (<= topk of them) ----
        if (tid < kept) {
            int ps = s_cs > s_ks[tid] ? s_cs : s_ks[tid];
            int pe = s_ce < s_ke[tid] ? s_ce : s_ke[tid];
            if (pe >= ps) {
                float d = 0.0f;
                for (int k = ps; k <= pe; ++k)
                    d += fabsf(s_cxs[k] - s_kxs[tid][k]);
                float cnt = (float)(pe - ps + 1);
                if (d / cnt < thr) s_sup = 1;          // benign same-value race
            }
        }
        __syncthreads();

        if (!s_sup) {                                  // uniform branch
            if (tid < N_OFF) s_kxs[kept][tid] = s_cxs[tid];
            if (tid == 0) { s_ks[kept] = s_cs; s_ke[kept] = s_ce; }
            if (tid < PROW) out[kept * (PROW + 1) + tid] = prop[(size_t)w * PROW + tid];
            if (tid == PROW) out[kept * (PROW + 1) + PROW] = scores[w];
            ++kept;                                    // uniform update
            if (kept >= topk) break;                   // uniform
        }
        __syncthreads();
    }

    // zero-fill unused rows (d_out is poisoned 0xAA before every timed call)
    for (int i = tid; i < (out_rows - kept) * (PROW + 1); i += NTH)
        out[kept * (PROW + 1) + i] = 0.0f;
    // num_kept == kept in both exit branches (saturated at topk, or pool
    // exhausted in which case kept == total greedy-kept count)
    if (tid == 0) out[out_rows * (PROW + 1)] = (float)kept;
}

extern "C" void kernel_launch(void* const* d_in, const int* in_sizes, int n_in,
                              void* d_out, int out_size, void* d_ws, size_t ws_size,
                              hipStream_t stream) {
    const float* prop   = (const float*)d_in[0];
    const float* scores = (const float*)d_in[1];
    const int*   thres  = (const int*)d_in[2];
    const int*   topk   = (const int*)d_in[3];
    int n        = in_sizes[1];
    int out_rows = (out_size - 1) / (PROW + 1);   // 624/78 = 8
    lane_nms<<<1, NTH, 0, stream>>>(prop, scores, thres, topk,
                                    (float*)d_out, n, out_rows);
}

// Round 2
// 88.400 us; speedup vs baseline: 1.0197x; 1.0197x over previous
//
#include <hip/hip_runtime.h>

// LaneATT greedy line-NMS, lazy formulation, pipelined.
//
// Key facts exploited:
//  * Lazy NMS pops proposals in strict global (score desc, idx asc) order;
//    popping removes only the popped item, so the pop sequence is just the
//    sorted-order prefix until topk are kept.
//  * Keys are unique 64-bit (score_bits<<32 | ~idx), so "argmax of alive"
//    == "argmax of keys strictly < last popped key" — no removal state.
//  * Therefore winner i+1 is known while classifying winner i: double-buffer
//    the 78-float candidate row in LDS and prefetch 2 iterations ahead,
//    hiding the ~900-cycle HBM row fetch behind scan+classify.
//
// 256 threads (4 waves) on one CU: cheap barriers, 2 per iteration.

#define NTH    256
#define SLOTS  32            // NTH*SLOTS = 8192 >= n
#define NWAVES (NTH / 64)
#define N_OFF  72
#define NSTRIP 71
#define PROW   77
#define MAXK   8

__device__ __forceinline__ unsigned long long pack_key(float s, int idx) {
    return ((unsigned long long)__float_as_uint(s) << 32) |
           (unsigned long long)(0xFFFFFFFFu - (unsigned)idx);
}
__device__ __forceinline__ int key_idx(unsigned long long k) {
    return (int)(0xFFFFFFFFu - (unsigned)(k & 0xFFFFFFFFu));
}

__global__ __launch_bounds__(NTH, 1) void lane_nms(
    const float* __restrict__ prop,
    const float* __restrict__ scores,
    const int* __restrict__ p_thres,
    const int* __restrict__ p_topk,
    float* __restrict__ out,
    int n, int out_rows)
{
    const int tid  = threadIdx.x;
    const int lane = tid & 63;
    const int wv   = tid >> 6;

    __shared__ unsigned long long s_wmax[NWAVES];
    __shared__ float s_buf[2][PROW + 1];          // candidate row + score
    __shared__ float s_kxs[MAXK][N_OFF];          // kept rows' xs
    __shared__ int   s_ks[MAXK], s_ke[MAXK];
    __shared__ int   s_sup[2];                    // parity-indexed suppress flag

    const float thr = (float)(*p_thres);
    int topk = *p_topk;
    if (topk > out_rows) topk = out_rows;
    if (topk > MAXK)     topk = MAXK;

    // ---- build keys: 32 per thread, float4 score loads ----
    unsigned long long key[SLOTS];
#pragma unroll
    for (int jo = 0; jo < SLOTS / 4; ++jo) {
        int base = jo * (NTH * 4) + tid * 4;
        if (base + 3 < n) {
            const float4 s4 = *reinterpret_cast<const float4*>(scores + base);
            key[jo * 4 + 0] = pack_key(s4.x, base + 0);
            key[jo * 4 + 1] = pack_key(s4.y, base + 1);
            key[jo * 4 + 2] = pack_key(s4.z, base + 2);
            key[jo * 4 + 3] = pack_key(s4.w, base + 3);
        } else {
#pragma unroll
            for (int c = 0; c < 4; ++c) {
                int idx = base + c;
                key[jo * 4 + c] = (idx < n) ? pack_key(scores[idx], idx) : 0ULL;
            }
        }
    }
    if (tid == 0) { s_sup[0] = 0; s_sup[1] = 0; }

    // scan: max over keys strictly < lim (0 == none). Writes s_wmax[wv].
    auto scan = [&](unsigned long long lim) {
        unsigned long long m = 0ULL;
#pragma unroll
        for (int j = 0; j < SLOTS; ++j) {
            unsigned long long k = key[j];
            if (k < lim && k > m) m = k;
        }
#pragma unroll
        for (int off = 32; off > 0; off >>= 1) {
            unsigned long long o = __shfl_down(m, off);
            if (o > m) m = o;
        }
        if (lane == 0) s_wmax[wv] = m;
    };
    auto merge = [&]() {                      // after a barrier; broadcast reads
        unsigned long long m = s_wmax[0];
#pragma unroll
        for (int i = 1; i < NWAVES; ++i)
            if (s_wmax[i] > m) m = s_wmax[i];
        return m;
    };

    // ---- prologue: top-2, prefetch both rows ----
    scan(~0ULL);
    __syncthreads();
    unsigned long long k1 = merge();
    __syncthreads();                          // protect s_wmax reuse
    scan(k1);
    __syncthreads();
    unsigned long long k2 = merge();

    if (k1 != 0ULL) {
        int w = key_idx(k1);
        if (tid < PROW)       s_buf[0][tid]  = prop[(size_t)w * PROW + tid];
        else if (tid == PROW) s_buf[0][PROW] = scores[w];
    }
    if (k2 != 0ULL) {
        int w = key_idx(k2);
        if (tid >= NTH - PROW - 1) {          // different threads: more MLP
            int t = tid - (NTH - PROW - 1);
            s_buf[1][t] = (t < PROW) ? prop[(size_t)w * PROW + t] : scores[w];
        }
    }
    __syncthreads();                          // drains prefetches, s_wmax reads

    int kept = 0, p = 0, q = 0;
    unsigned long long curk = k1, nxtk = k2;

    if (topk > 0) {
        while (curk != 0ULL) {
            // -- step 1: scan (for winner i+2) + classify winner i, 1 barrier --
            scan(nxtk);                       // nxtk==0 -> result 0 naturally
            float sy = s_buf[p][2];
            float ln = s_buf[p][4];
            int cs = (int)rintf(sy * (float)NSTRIP);   // half-even == jnp.round
            int ce = cs + (int)rintf(ln) - 1;
            if (ce > NSTRIP) ce = NSTRIP;
            if (tid < kept) {
                int ps = cs > s_ks[tid] ? cs : s_ks[tid];
                int pe = ce < s_ke[tid] ? ce : s_ke[tid];
                if (pe >= ps) {
                    float d = 0.0f;
                    for (int k = ps; k <= pe; ++k)
                        d += fabsf(s_buf[p][5 + k] - s_kxs[tid][k]);
                    if (d / (float)(pe - ps + 1) < thr) s_sup[q] = 1;
                }
            }
            if (tid == NTH - 1) s_sup[q ^ 1] = 0;      // reset other parity
            __syncthreads();                           // A

            unsigned long long k3 = merge();
            if (s_sup[q] == 0) {                       // uniform keep decision
                if (tid < PROW + 1) out[kept * (PROW + 1) + tid] = s_buf[p][tid];
                if (tid < N_OFF)    s_kxs[kept][tid] = s_buf[p][5 + tid];
                if (tid == 0) { s_ks[kept] = cs; s_ke[kept] = ce; }
                ++kept;
                if (kept >= topk) break;               // uniform
            }
            __syncthreads();                           // B: bufs/flags reusable

            // -- prefetch winner i+2 into the buffer just freed --
            if (k3 != 0ULL) {
                int w = key_idx(k3);
                if (tid < PROW)       s_buf[p][tid]  = prop[(size_t)w * PROW + tid];
                else if (tid == PROW) s_buf[p][PROW] = scores[w];
            }
            curk = nxtk; nxtk = k3; p ^= 1; q ^= 1;
        }
    }

    // ---- epilogue: zero unused rows (d_out poisoned 0xAA), write count ----
    for (int i = tid; i < (out_rows - kept) * (PROW + 1); i += NTH)
        out[kept * (PROW + 1) + i] = 0.0f;
    if (tid == 0) out[out_rows * (PROW + 1)] = (float)kept;
}

extern "C" void kernel_launch(void* const* d_in, const int* in_sizes, int n_in,
                              void* d_out, int out_size, void* d_ws, size_t ws_size,
                              hipStream_t stream) {
    const float* prop   = (const float*)d_in[0];
    const float* scores = (const float*)d_in[1];
    const int*   thres  = (const int*)d_in[2];
    const int*   topk   = (const int*)d_in[3];
    int n        = in_sizes[1];
    int out_rows = (out_size - 1) / (PROW + 1);   // 624/78 = 8
    lane_nms<<<1, NTH, 0, stream>>>(prop, scores, thres, topk,
                                    (float*)d_out, n, out_rows);
}